// Round 3
// baseline (103.517 us; speedup 1.0000x reference)
//
#include <hip/hip_runtime.h>
#include <stdint.h>

#define B_    32
#define CH    64
#define T_    16384
#define NC    129     // noise coeffs
#define NFRM  128     // frames
#define QPAD  136     // padded coeff rows in spec_ws (17*8)
#define MROWS 144     // padded W rows (9 MFMA tiles)

typedef __attribute__((ext_vector_type(4))) float f32x4;
typedef __attribute__((ext_vector_type(4))) int   i32x4;
typedef __attribute__((ext_vector_type(8))) short bf16x8;

// Legacy raw-buffer-load intrinsics (CK-style declarations, stable on ROCm).
__device__ float llvm_amdgcn_raw_buffer_load_f32(i32x4 rsrc, int voffset, int soffset, int aux) __asm("llvm.amdgcn.raw.buffer.load.f32");
__device__ f32x4 llvm_amdgcn_raw_buffer_load_v4f32(i32x4 rsrc, int voffset, int soffset, int aux) __asm("llvm.amdgcn.raw.buffer.load.v4f32");

__device__ __forceinline__ unsigned short f2bs(float f) {
  union { float f; unsigned u; } v; v.f = f;
  unsigned r = (v.u + 0x7FFFu + ((v.u >> 16) & 1u)) >> 16;
  return (unsigned short)r;
}
__device__ __forceinline__ float b2f(unsigned short s) {
  union { float f; unsigned u; } v; v.u = ((unsigned)s) << 16; return v.f;
}
// truncating bf16 pack of 2 floats -> one dword (single v_perm_b32)
__device__ __forceinline__ unsigned pk2(float lo, float hi) {
  return __builtin_amdgcn_perm(__float_as_uint(hi), __float_as_uint(lo), 0x07060302u);
}
__device__ __forceinline__ i32x4 make_srsrc_wave(const void* p) {
  unsigned long long a = (unsigned long long)p;
  i32x4 r;
  r[0] = __builtin_amdgcn_readfirstlane((int)(unsigned)a);
  r[1] = __builtin_amdgcn_readfirstlane(((int)(unsigned)(a >> 32)) & 0xFFFF);
  r[2] = -1;            // num_records: disable bounds check (all accesses in-range)
  r[3] = 0x00020000;
  return r;
}

// ---------------------------------------------------------------------------
// k0: DFT tables (blocks 0..63) + W pack linear bf16 + bias (blocks 64..68).
// ---------------------------------------------------------------------------
__global__ __launch_bounds__(256) void k0_setup(
    unsigned short* __restrict__ T1, unsigned short* __restrict__ T2,
    const float* __restrict__ nw, const float* __restrict__ nb,
    unsigned short* __restrict__ wb_ws, float* __restrict__ bias_ws) {
  int bid = blockIdx.x;
  if (bid < 64) {
    int g = bid * 256 + threadIdx.x;
    int base = g * 8;
    int tab = base >> 16;
    int off = base & 65535;
    int row = off >> 8, col0 = off & 255;
    const float w0 = 6.283185307179586f / 256.f;
    bf16x8 pk;
#pragma unroll
    for (int e = 0; e < 8; ++e) {
      int cq = col0 + e;
      float v;
      if (tab == 0) {  // T1[q][m]
        int q = row, m = cq;
        int idx = (q <= 128) ? ((q * m) & 255) : (((q - 128) * m + 192) & 255);
        v = cosf((float)idx * w0);
      } else {         // T2[n][q]
        int n = row, q = cq;
        float c = (q == 0 || q == 128) ? 1.f : 2.f;
        int idx = (q <= 128) ? ((q * n) & 255) : (((q - 128) * n + 192) & 255);
        v = c * cosf((float)idx * w0);
      }
      pk[e] = (short)f2bs(v);
    }
    *(bf16x8*)((tab ? T2 : T1) + off) = pk;
  } else {
    int t = (bid - 64) * 256 + threadIdx.x;  // 0..1279
    if (t < MROWS * 8) {
      int q = t >> 3, o = t & 7;
      bf16x8 pk;
#pragma unroll
      for (int e = 0; e < 8; ++e)
        pk[e] = (q < NC) ? (short)f2bs(nw[q * 64 + o * 8 + e]) : (short)0;
      *(bf16x8*)(wb_ws + q * 64 + o * 8) = pk;
    }
    if (t < MROWS) bias_ws[t] = (t < NC) ? nb[t] : 0.f;
  }
}

// ---------------------------------------------------------------------------
// k1 v3: zero-LDS, zero-barrier. One WAVE = one (b, frame j). x loaded
// directly into MFMA B-fragment lanes via buffer loads; bias as MFMA C-in;
// clip via fmed3; spec partials in registers; mean from same registers.
// ---------------------------------------------------------------------------
__global__ __launch_bounds__(256, 4) void k1_spec_mean(
    const float* __restrict__ x, const unsigned short* __restrict__ wb_ws,
    const float* __restrict__ bias_ws, float* __restrict__ out,
    unsigned short* __restrict__ spec_ws) {
  const int tid = threadIdx.x;
  const int w = tid >> 6, lane = tid & 63;
  const int l15 = lane & 15, l4 = lane >> 4;
  const int b = blockIdx.y;
  const int j = blockIdx.x * 4 + w;

  // bias fragments (C-input rows: q = m*16 + l4*4 + r)
  f32x4 biasf[9];
  const float* bp = bias_ws + l4 * 4;
#pragma unroll
  for (int m = 0; m < 9; ++m)
#pragma unroll
    for (int r = 0; r < 4; ++r) biasf[m][r] = bp[m * 16 + r];

  i32x4 rx = make_srsrc_wave(x + (size_t)b * CH * T_ + (size_t)j * 128);
  i32x4 rw = make_srsrc_wave(wb_ws);
  const int vx = (l4 * 8 * T_ + l15) * 4;       // lane offset into x (bytes)
  const int vw = l15 * 128 + l4 * 16;           // lane offset into W (bytes)

  f32x4 spec_part[9];
#pragma unroll
  for (int m = 0; m < 9; ++m) spec_part[m] = (f32x4){0.f, 0.f, 0.f, 0.f};

  float* op = out + (size_t)b * T_ + (size_t)j * 128;

  for (int tt = 0; tt < 8; ++tt) {
    const int vt = vx + tt * 64;
    float f[16];
#pragma unroll
    for (int kt = 0; kt < 2; ++kt)
#pragma unroll
      for (int e = 0; e < 8; ++e)
        f[kt * 8 + e] =
            llvm_amdgcn_raw_buffer_load_f32(rx, vt, (kt * 32 + e) * (T_ * 4), 0);

    // channel mean for t = tt*16 + l15 (fp32)
    float ms = 0.f;
#pragma unroll
    for (int e = 0; e < 16; ++e) ms += f[e];
    ms += __shfl_xor(ms, 16);
    ms += __shfl_xor(ms, 32);
    if (l4 == 0) op[tt * 16 + l15] = ms * (1.f / 64.f);

    // pack B-fragments (truncating bf16)
    union { unsigned u[4]; bf16x8 h; } bu0, bu1;
#pragma unroll
    for (int p = 0; p < 4; ++p) {
      bu0.u[p] = pk2(f[2 * p], f[2 * p + 1]);
      bu1.u[p] = pk2(f[8 + 2 * p], f[8 + 2 * p + 1]);
    }

#pragma unroll
    for (int m = 0; m < 9; ++m) {
      union { f32x4 f; bf16x8 h; } a0, a1;
      a0.f = llvm_amdgcn_raw_buffer_load_v4f32(rw, vw, m * 2048, 0);
      a1.f = llvm_amdgcn_raw_buffer_load_v4f32(rw, vw + 64, m * 2048, 0);
      f32x4 acc = biasf[m];
      acc = __builtin_amdgcn_mfma_f32_16x16x32_bf16(a0.h, bu0.h, acc, 0, 0, 0);
      acc = __builtin_amdgcn_mfma_f32_16x16x32_bf16(a1.h, bu1.h, acc, 0, 0, 0);
#pragma unroll
      for (int r = 0; r < 4; ++r)
        spec_part[m][r] += __builtin_amdgcn_fmed3f(acc[r], 0.f, 1.f);
    }
  }

  // frame-mean reduce (over the 16 t-columns held across l15) + store bf16
  unsigned short* sp = spec_ws + ((size_t)b * NFRM + j) * QPAD;
#pragma unroll
  for (int m = 0; m < 9; ++m)
#pragma unroll
    for (int r = 0; r < 4; ++r) {
      float s = spec_part[m][r];
      s += __shfl_xor(s, 1);
      s += __shfl_xor(s, 2);
      s += __shfl_xor(s, 4);
      s += __shfl_xor(s, 8);
      int q = m * 16 + l4 * 4 + r;
      if (l15 == 0 && q < QPAD) sp[q] = f2bs(s * (1.f / 128.f));
    }
}

// ---------------------------------------------------------------------------
// k2: noise bank. Chunk = 16 frames -> grid (8, 32) = 256 blocks.
// Slots s=0..16 map to frames j = c*16-1+s (slot 0 = tail provider, spec=0
// for j<0). N padded to 32 slots (s>=17 garbage, masked by spec=0 & unread).
// ---------------------------------------------------------------------------
__global__ __launch_bounds__(512) void k2_noise(
    const float* __restrict__ white, const unsigned short* __restrict__ spec_ws,
    const unsigned short* __restrict__ T1, const unsigned short* __restrict__ T2,
    const float* __restrict__ nf_p, float* __restrict__ out) {
  __shared__ __align__(16) unsigned short wn[4224];           // 8.25 KB swz
  __shared__ __align__(16) unsigned short spec_l[32 * QPAD];  // 8.5 KB
  __shared__ __align__(16) unsigned short G[32 * 256];        // 16 KB swz
  __shared__ __align__(16) unsigned short audio[256 * 33];    // 16.5 KB bf16

  const int c = blockIdx.x, b = blockIdx.y;
  const int jb = c * 16 - 1;
  const int tid = threadIdx.x;
  const int lane = tid & 63, w = tid >> 6;
  const int l15 = lane & 15, l4 = lane >> 4;

  // stage white frames source: 528 swizzled octets (s<17 valid, rest zero)
  for (int rc = tid; rc < 528; rc += 512) {
    int g0 = jb * 128 + rc * 8;
    bf16x8 pk;
    if (rc < 288 && (unsigned)g0 < (unsigned)T_) {
      const float* wp = white + (size_t)b * T_ + g0;
      union { unsigned u[4]; bf16x8 h; } t;
#pragma unroll
      for (int p = 0; p < 4; ++p) t.u[p] = pk2(wp[2 * p], wp[2 * p + 1]);
      pk = t.h;
    } else {
#pragma unroll
      for (int e = 0; e < 8; ++e) pk[e] = 0;
    }
    unsigned a = rc * 16;
    a ^= ((a >> 8) & 7) << 4;
    *(bf16x8*)((char*)wn + a) = pk;
  }
  // stage spec: 32 slots x 17 uint4 (s>=17 or frame OOR -> 0)
  for (int ec = tid; ec < 32 * 17; ec += 512) {
    int s = ec / 17, cr = ec % 17;
    int jj = jb + s;
    uint4 vv = make_uint4(0u, 0u, 0u, 0u);
    if (s < 17 && (unsigned)jj < 128u)
      vv = *(const uint4*)(spec_ws + ((size_t)b * NFRM + jj) * QPAD + cr * 8);
    *(uint4*)(spec_l + s * QPAD + cr * 8) = vv;
  }
  __syncthreads();

  const f32x4 fz = {0.f, 0.f, 0.f, 0.f};
  // GEMM1: CS[q, s] = sum_m T1[q,m] * frames[m,s]; wave w -> q-tiles {2w,2w+1}
  f32x4 acc[2][2];
#pragma unroll
  for (int mi = 0; mi < 2; ++mi)
#pragma unroll
    for (int nt = 0; nt < 2; ++nt) acc[mi][nt] = fz;
#pragma unroll
  for (int kt = 0; kt < 8; ++kt) {
    bf16x8 bfr[2];
#pragma unroll
    for (int nt = 0; nt < 2; ++nt) {
      int s = nt * 16 + l15;
      unsigned a = s * 256 + kt * 64 + l4 * 16;
      a ^= ((a >> 8) & 7) << 4;
      bfr[nt] = *(const bf16x8*)((const char*)wn + a);
    }
#pragma unroll
    for (int mi = 0; mi < 2; ++mi) {
      int q = (2 * w + mi) * 16 + l15;
      bf16x8 afr = *(const bf16x8*)(T1 + q * 256 + kt * 32 + l4 * 8);
#pragma unroll
      for (int nt = 0; nt < 2; ++nt)
        acc[mi][nt] = __builtin_amdgcn_mfma_f32_16x16x32_bf16(afr, bfr[nt], acc[mi][nt], 0, 0, 0);
    }
  }
  // scale by spec -> G (bf16, swizzled), packed pair writes
#pragma unroll
  for (int mi = 0; mi < 2; ++mi) {
    int qbase = (2 * w + mi) * 16 + l4 * 4;
#pragma unroll
    for (int nt = 0; nt < 2; ++nt) {
      int s = nt * 16 + l15;
#pragma unroll
      for (int rp = 0; rp < 2; ++rp) {
        int q0 = qbase + rp * 2;
        int kk0 = (q0 <= 128) ? q0 : q0 - 128;
        int kk1 = (q0 + 1 <= 128) ? q0 + 1 : q0 - 127;
        float s0 = b2f(spec_l[s * QPAD + kk0]);
        float s1 = b2f(spec_l[s * QPAD + kk1]);
        unsigned pw = pk2(acc[mi][nt][rp * 2] * s0, acc[mi][nt][rp * 2 + 1] * s1);
        unsigned a = s * 512 + q0 * 2;
        a ^= ((a >> 9) & 7) << 4;
        *(unsigned*)((char*)G + a) = pw;
      }
    }
  }
  __syncthreads();

  // GEMM2: audio[n, s] = sum_q T2[n,q] * G[q,s]
  f32x4 acc2[2][2];
#pragma unroll
  for (int mi = 0; mi < 2; ++mi)
#pragma unroll
    for (int nt = 0; nt < 2; ++nt) acc2[mi][nt] = fz;
#pragma unroll
  for (int kt = 0; kt < 8; ++kt) {
    bf16x8 bfr[2];
#pragma unroll
    for (int nt = 0; nt < 2; ++nt) {
      int s = nt * 16 + l15;
      unsigned a = s * 512 + kt * 64 + l4 * 16;
      a ^= ((a >> 9) & 7) << 4;
      bfr[nt] = *(const bf16x8*)((const char*)G + a);
    }
#pragma unroll
    for (int mi = 0; mi < 2; ++mi) {
      int n = (2 * w + mi) * 16 + l15;
      bf16x8 afr = *(const bf16x8*)(T2 + n * 256 + kt * 32 + l4 * 8);
#pragma unroll
      for (int nt = 0; nt < 2; ++nt)
        acc2[mi][nt] = __builtin_amdgcn_mfma_f32_16x16x32_bf16(afr, bfr[nt], acc2[mi][nt], 0, 0, 0);
    }
  }
  // audio -> LDS (bf16, [n][s] pad 33)
#pragma unroll
  for (int mi = 0; mi < 2; ++mi)
#pragma unroll
    for (int nt = 0; nt < 2; ++nt)
#pragma unroll
      for (int r = 0; r < 4; ++r) {
        int n = (2 * w + mi) * 16 + l4 * 4 + r;
        int s = nt * 16 + l15;
        audio[n * 33 + s] = f2bs(acc2[mi][nt][r]);
      }
  __syncthreads();

  // OLA + scaled add into out (out already holds the channel mean)
  const float cf = nf_p[0] * (1.f / 256.f);
  {
    int t0 = tid * 4;            // [0, 2048)
    int n = t0 & 127, jl = t0 >> 7;
    int s1 = jl + 1;
    size_t o = (size_t)b * T_ + (size_t)c * 2048 + t0;
    f32x4 ov = *(f32x4*)(out + o);
#pragma unroll
    for (int e = 0; e < 4; ++e) {
      float a1 = b2f(audio[(n + e) * 33 + s1]);
      float a2 = b2f(audio[(n + e + 128) * 33 + jl]);
      ov[e] += cf * (a1 + a2);
    }
    *(f32x4*)(out + o) = ov;
  }
}

// ---------------------------------------------------------------------------
extern "C" void kernel_launch(void* const* d_in, const int* in_sizes, int n_in,
                              void* d_out, int out_size, void* d_ws, size_t ws_size,
                              hipStream_t stream) {
  (void)in_sizes; (void)n_in; (void)out_size; (void)ws_size;
  const float* x            = (const float*)d_in[0];
  const float* noise_w      = (const float*)d_in[5];
  const float* noise_b      = (const float*)d_in[6];
  const float* noise_factor = (const float*)d_in[7];
  const float* white        = (const float*)d_in[8];
  float* out = (float*)d_out;

  unsigned short* T1    = (unsigned short*)d_ws;           // 65536 bf16
  unsigned short* T2    = T1 + 65536;                      // 65536 bf16
  unsigned short* spec  = T2 + 65536;                      // 32*128*136 bf16
  unsigned short* wb_ws = spec + (size_t)B_ * NFRM * QPAD; // 144*64 bf16 linear
  float*          bias_ws = (float*)(wb_ws + MROWS * 64);  // 144 f32

  k0_setup<<<69, 256, 0, stream>>>(T1, T2, noise_w, noise_b, wb_ws, bias_ws);
  k1_spec_mean<<<dim3(32, B_), 256, 0, stream>>>(x, wb_ws, bias_ws, out, spec);
  k2_noise<<<dim3(8, B_), 512, 0, stream>>>(white, spec, T1, T2, noise_factor, out);
}